// Round 13
// baseline (318.790 us; speedup 1.0000x reference)
//
#include <hip/hip_runtime.h>
#include <hip/hip_bf16.h>
#include <stdint.h>

#define DIM   1024
#define ODIM  3072
#define MROWS 32768   // B(8) * N(4096)
#define RANK  8

typedef unsigned short u16;
typedef __attribute__((ext_vector_type(8))) short short8;
typedef __attribute__((ext_vector_type(8))) unsigned short u16x8;
typedef __attribute__((ext_vector_type(4))) unsigned short u16x4;
typedef __attribute__((ext_vector_type(16))) float f32x16;

__device__ __forceinline__ u16 f2bf(float f) {
    uint32_t u = __float_as_uint(f);
    u += 0x7fffu + ((u >> 16) & 1u);   // RNE
    return (u16)(u >> 16);
}

__device__ __forceinline__ void gl2lds16(const void* g, void* l) {
    __builtin_amdgcn_global_load_lds(
        (const __attribute__((address_space(1))) void*)(uintptr_t)g,
        (__attribute__((address_space(3))) void*)(uint32_t)(uintptr_t)l,
        16, 0, 0);
}

#define BAR()    do { asm volatile("" ::: "memory"); __builtin_amdgcn_s_barrier(); asm volatile("" ::: "memory"); } while (0)
#define WAITV4() asm volatile("s_waitcnt vmcnt(4)" ::: "memory")
#define WAITV2() asm volatile("s_waitcnt vmcnt(2)" ::: "memory")
#define WAITV0() asm volatile("s_waitcnt vmcnt(0)" ::: "memory")
#define WAITL0() asm volatile("s_waitcnt lgkmcnt(0)" ::: "memory")
#define WAITL8() asm volatile("s_waitcnt lgkmcnt(8)" ::: "memory")
#define SCHED0() __builtin_amdgcn_sched_barrier(0)

// ---------------- f32 -> bf16 conversion ----------------
__global__ __launch_bounds__(256) void k_convert(const float* __restrict__ src,
                                                 u16* __restrict__ dst, int n) {
    const int stride = gridDim.x * blockDim.x;
    for (int t = blockIdx.x * blockDim.x + threadIdx.x; t * 8 < n; t += stride) {
        const int i = t * 8;
        float4 a = *reinterpret_cast<const float4*>(src + i);
        float4 b = *reinterpret_cast<const float4*>(src + i + 4);
        u16x8 o;
        o[0] = f2bf(a.x); o[1] = f2bf(a.y); o[2] = f2bf(a.z); o[3] = f2bf(a.w);
        o[4] = f2bf(b.x); o[5] = f2bf(b.y); o[6] = f2bf(b.z); o[7] = f2bf(b.w);
        *reinterpret_cast<u16x8*>(dst + i) = o;
    }
}

// -------- Wmod[b] = W_slab + (A[idx_b]@B[idx_b])^T (blocks 0..1023) ------------
// -------- + plain convert of W_k slab (blocks 1024..1535)           ------------
__global__ __launch_bounds__(256) void k_build(const float* __restrict__ W,
                                               const float* __restrict__ Aq_pool,
                                               const float* __restrict__ Bq_pool,
                                               const float* __restrict__ Av_pool,
                                               const float* __restrict__ Bv_pool,
                                               const int* __restrict__ idx,
                                               u16* __restrict__ Wmq,
                                               u16* __restrict__ Wmv,
                                               u16* __restrict__ Wk) {
    if (blockIdx.x >= 1024) {                      // Wk convert: 512 blocks
        const int bb = blockIdx.x - 1024;
        const int i = (bb * 256 + threadIdx.x) * 8;
        const float* src = W + (size_t)DIM * DIM + i;
        float4 a = *reinterpret_cast<const float4*>(src);
        float4 b = *reinterpret_cast<const float4*>(src + 4);
        u16x8 o;
        o[0] = f2bf(a.x); o[1] = f2bf(a.y); o[2] = f2bf(a.z); o[3] = f2bf(a.w);
        o[4] = f2bf(b.x); o[5] = f2bf(b.y); o[6] = f2bf(b.z); o[7] = f2bf(b.w);
        *reinterpret_cast<u16x8*>(Wk + i) = o;
        return;
    }
    const int b  = blockIdx.x >> 7;
    const int s  = (blockIdx.x >> 6) & 1;
    const int og = blockIdx.x & 63;
    const int p  = idx[b];
    const float* A  = (s ? Av_pool : Aq_pool) + (size_t)p * DIM * RANK;
    const float* Bp = (s ? Bv_pool : Bq_pool) + (size_t)p * RANK * DIM;
    const float* Ws = W + (size_t)(s ? 2048 : 0) * DIM;
    u16* dst = (s ? Wmv : Wmq) + (size_t)b * DIM * DIM;

    const int t  = threadIdx.x;
    const int i0 = t * 4;
    float a[4][8];
    #pragma unroll
    for (int ii = 0; ii < 4; ++ii) {
        float4 a0 = reinterpret_cast<const float4*>(A + (size_t)(i0 + ii) * RANK)[0];
        float4 a1 = reinterpret_cast<const float4*>(A + (size_t)(i0 + ii) * RANK)[1];
        a[ii][0] = a0.x; a[ii][1] = a0.y; a[ii][2] = a0.z; a[ii][3] = a0.w;
        a[ii][4] = a1.x; a[ii][5] = a1.y; a[ii][6] = a1.z; a[ii][7] = a1.w;
    }
    for (int r = 0; r < 16; ++r) {
        const int o = og * 16 + r;
        float bv[8];
        #pragma unroll
        for (int rr = 0; rr < 8; ++rr) bv[rr] = Bp[(size_t)rr * DIM + o];
        float4 w = *reinterpret_cast<const float4*>(Ws + (size_t)o * DIM + i0);
        float v[4] = {w.x, w.y, w.z, w.w};
        u16x4 ov;
        #pragma unroll
        for (int ii = 0; ii < 4; ++ii) {
            float d = 0.f;
            #pragma unroll
            for (int rr = 0; rr < 8; ++rr) d += a[ii][rr] * bv[rr];
            ov[ii] = f2bf(v[ii] + d);
        }
        *reinterpret_cast<u16x4*>(dst + (size_t)o * DIM + i0) = ov;
    }
}

// ---------------- 256x256 8-wave 8-phase GEMM, 32x32x16 MFMA ----------------
// R9 base (count-guaranteed vmcnt ledger, byte-identical LDS layout/staging);
// only the MFMA shape + fragment map changes.
// LDS: 2 buf x (A 256x64 + B 256x64) = 128 KiB; row r (64 u16 = 128B),
// 16B group g at slot g^(r&7); stage via pre-swizzled global src (rule #21).
// A-frag F (0..3, 32 rows): rows wr*64 + (F&1)*32 + (F>>1)*128  (F<2 -> half0)
// B-frag G (0..1, 32 rows): rows wc*32 + G*128                   (G=0 -> half0)
// Read (32x32x16): lane l -> row r = r0+(l&31) (r&7 == l&7), k-group
// gk = 2*ks + (l>>5) -> addr = r*64 + (gk ^ (l&7))*8. Per-8-lane beat: 8
// distinct slots -> conflict-free (same relation as R9's measured-0 reads).
// C/D (m74/m101): col = lane&31, row = (v&3) + 8*(v>>2) + 4*(lane>>5).
// Phases/vmcnt identical to R9: stage A0@0,B0@1,B1@2,A1@3; WAITV4 at ph0,ph1,
// ph3; tail drain 4->2->0. 8 MFMA(32x32)/phase.

__device__ __forceinline__ void stage_half(const u16* __restrict__ mat, int row0, int tk,
                                           u16* dst, int wave, int lane) {
    const int lrow = lane >> 3;
    const int g    = (lane & 7) ^ lrow;          // pre-swizzled 16B group
    const u16* gp = mat + (size_t)(row0 + wave * 8 + lrow) * DIM + tk + g * 8;
    u16* lp = dst + wave * 8 * 64;               // wave-uniform LDS base
    gl2lds16(gp, lp);
    gl2lds16(gp + (size_t)64 * DIM, lp + 64 * 64);
}

// read one 32-row fragment, 4 k-subtiles
__device__ __forceinline__ void ds_read_frag(const u16* base, int r0, int lane,
                                             short8 (&v)[4]) {
    const int row = r0 + (lane & 31);
    const int x7  = lane & 7;
    const int kb  = lane >> 5;
    #pragma unroll
    for (int ks = 0; ks < 4; ++ks)
        v[ks] = *reinterpret_cast<const short8*>(base + row * 64 + ((2 * ks + kb) ^ x7) * 8);
}

#define MFMA_QUAD(MH, NH, A0, A1, BREG)                                           \
    do {                                                                          \
        BAR();                                                                    \
        WAITL0();                                                                 \
        SCHED0();                                                                 \
        __builtin_amdgcn_s_setprio(1);                                            \
        _Pragma("unroll")                                                         \
        for (int ks = 0; ks < 4; ++ks) {                                          \
            acc[2 * MH][NH]     = __builtin_amdgcn_mfma_f32_32x32x16_bf16(        \
                A0[ks], BREG[ks], acc[2 * MH][NH], 0, 0, 0);                      \
            acc[2 * MH + 1][NH] = __builtin_amdgcn_mfma_f32_32x32x16_bf16(        \
                A1[ks], BREG[ks], acc[2 * MH + 1][NH], 0, 0, 0);                  \
        }                                                                         \
        __builtin_amdgcn_s_setprio(0);                                            \
        SCHED0();                                                                 \
    } while (0)

__global__ __launch_bounds__(512, 2) void k_gemm(const u16* __restrict__ Xc,
                                                 const u16* __restrict__ Wk,
                                                 const u16* __restrict__ Wmq,
                                                 const u16* __restrict__ Wmv,
                                                 const float* __restrict__ bias,
                                                 float* __restrict__ out) {
    extern __shared__ u16 lds[];               // 128 KiB
    const int tid  = threadIdx.x;
    const int lane = tid & 63, wave = tid >> 6;
    const int wr = wave >> 2, wc = wave & 3;   // 2M x 4N wave grid

    // bijective XCD swizzle (nwg=1536, 1536%8==0)
    const int orig = blockIdx.x;
    const int wg   = (orig & 7) * 192 + (orig >> 3);
    const int bn   = wg % 12;
    const int bm   = wg / 12;
    const int m0 = bm * 256, n0 = bn * 256;
    const int batch = m0 >> 12;

    const u16* Bmat;
    int nc;
    if (n0 < DIM)           { Bmat = Wmq + (size_t)batch * DIM * DIM; nc = n0; }
    else if (n0 < 2 * DIM)  { Bmat = Wk;                              nc = n0 - DIM; }
    else                    { Bmat = Wmv + (size_t)batch * DIM * DIM; nc = n0 - 2 * DIM; }

    f32x16 acc[4][2] = {};

    // prologue: tile 0 fully into buffer 0, drain once
    stage_half(Xc,   m0,       0, lds,                    wave, lane);
    stage_half(Bmat, nc,       0, lds + 16384,            wave, lane);
    stage_half(Bmat, nc + 128, 0, lds + 16384 + 128 * 64, wave, lane);
    stage_half(Xc,   m0 + 128, 0, lds + 128 * 64,         wave, lane);
    WAITV0(); BAR();

    #pragma unroll 1
    for (int t = 0; t < 15; ++t) {
        const u16* sA = lds + (t & 1) * 32768;
        const u16* sB = sA + 16384;
        u16* wA = lds + ((t + 1) & 1) * 32768;
        u16* wB = wA + 16384;
        const int tk1 = (t + 1) * 64;
        short8 f0[4], f1[4], f2[4], f3[4], g0[4], g1[4];

        // ---- phase 0: read F0,F1 (8) + G0 (4); stage A0(t+1); quad(0,0) ----
        ds_read_frag(sA, wr * 64,       lane, f0);
        ds_read_frag(sA, wr * 64 + 32,  lane, f1);
        ds_read_frag(sB, wc * 32,       lane, g0);
        stage_half(Xc, m0, tk1, wA, wave, lane);
        WAITL8();
        MFMA_QUAD(0, 0, f0, f1, g0);
        WAITV4(); BAR();               // retire B1(t) (read next phase)

        // ---- phase 1: read G1 (4); stage B0(t+1); quad(0,1) ----
        ds_read_frag(sB, wc * 32 + 128, lane, g1);
        stage_half(Bmat, nc, tk1, wB, wave, lane);
        MFMA_QUAD(0, 1, f0, f1, g1);
        WAITV4(); BAR();               // retire A1(t) (read next phase)

        // ---- phase 2: read F2,F3 (8); stage B1(t+1); quad(1,0) ----
        ds_read_frag(sA, wr * 64 + 128, lane, f2);
        ds_read_frag(sA, wr * 64 + 160, lane, f3);
        stage_half(Bmat, nc + 128, tk1, wB + 128 * 64, wave, lane);
        MFMA_QUAD(1, 0, f2, f3, g0);
        BAR();

        // ---- phase 3: no reads; stage A1(t+1); quad(1,1); boundary ----
        stage_half(Xc, m0 + 128, tk1, wA + 128 * 64, wave, lane);
        MFMA_QUAD(1, 1, f2, f3, g1);
        WAITV4(); BAR();               // retire A0,B0(t+1) (read at ph0)
    }

    // ---- peeled tail: tile 15, no staging; count-guaranteed drain ----
    {
        const u16* sA = lds + 32768;   // 15 & 1 == 1
        const u16* sB = sA + 16384;
        short8 f0[4], f1[4], f2[4], f3[4], g0[4], g1[4];

        ds_read_frag(sA, wr * 64,       lane, f0);
        ds_read_frag(sA, wr * 64 + 32,  lane, f1);
        ds_read_frag(sB, wc * 32,       lane, g0);
        WAITL8();
        MFMA_QUAD(0, 0, f0, f1, g0);
        WAITV2(); BAR();               // retire B1(15) before its read

        ds_read_frag(sB, wc * 32 + 128, lane, g1);
        MFMA_QUAD(0, 1, f0, f1, g1);
        WAITV0(); BAR();               // retire A1(15) before its read

        ds_read_frag(sA, wr * 64 + 128, lane, f2);
        ds_read_frag(sA, wr * 64 + 160, lane, f3);
        MFMA_QUAD(1, 0, f2, f3, g0);
        BAR();

        MFMA_QUAD(1, 1, f2, f3, g1);
    }

    // ---------------- epilogue: bias + store ----------------
    // C/D 32x32: col = lane&31, row = (v&3) + 8*(v>>2) + 4*(lane>>5)
    const int cb = lane & 31;
    const int rv = 4 * (lane >> 5);
    float bcol[2];
    #pragma unroll
    for (int G = 0; G < 2; ++G) bcol[G] = bias[n0 + wc * 32 + G * 128 + cb];
    #pragma unroll
    for (int F = 0; F < 4; ++F) {
        const int rbase = m0 + wr * 64 + (F & 1) * 32 + (F >> 1) * 128 + rv;
        #pragma unroll
        for (int G = 0; G < 2; ++G) {
            const size_t col = (size_t)(n0 + wc * 32 + G * 128 + cb);
            #pragma unroll
            for (int v = 0; v < 16; ++v) {
                const size_t row = (size_t)(rbase + (v & 3) + 8 * (v >> 2));
                out[row * ODIM + col] = acc[F][G][v] + bcol[G];
            }
        }
    }
}

extern "C" void kernel_launch(void* const* d_in, const int* in_sizes, int n_in,
                              void* d_out, int out_size, void* d_ws, size_t ws_size,
                              hipStream_t stream) {
    const float* x      = (const float*)d_in[0];
    const float* weight = (const float*)d_in[1];
    const float* bias   = (const float*)d_in[2];
    const float* Aq     = (const float*)d_in[3];
    const float* Bq     = (const float*)d_in[4];
    const float* Av     = (const float*)d_in[5];
    const float* Bv     = (const float*)d_in[6];
    const int*   idx    = (const int*)d_in[7];
    float* out = (float*)d_out;

    // workspace: Xc(64MB) | Wk(2MB) | Wmq(16MB) | Wmv(16MB) = 98MB
    u16* Xc  = (u16*)d_ws;
    u16* Wk  = Xc + (size_t)MROWS * DIM;
    u16* Wmq = Wk + (size_t)DIM * DIM;
    u16* Wmv = Wmq + (size_t)8 * DIM * DIM;

    hipFuncSetAttribute(reinterpret_cast<const void*>(k_gemm),
                        hipFuncAttributeMaxDynamicSharedMemorySize, 131072);

    k_convert<<<2048, 256, 0, stream>>>(x, Xc, MROWS * DIM);
    k_build<<<1536, 256, 0, stream>>>(weight, Aq, Bq, Av, Bv, idx, Wmq, Wmv, Wk);
    k_gemm<<<1536, 512, 131072, stream>>>(Xc, Wk, Wmq, Wmv, bias, out);
}

// Round 14
// 285.421 us; speedup vs baseline: 1.1169x; 1.1169x over previous
//
#include <hip/hip_runtime.h>
#include <hip/hip_bf16.h>
#include <stdint.h>

#define DIM   1024
#define ODIM  3072
#define MROWS 32768   // B(8) * N(4096)
#define RANK  8

typedef unsigned short u16;
typedef __attribute__((ext_vector_type(8))) short short8;
typedef __attribute__((ext_vector_type(8))) unsigned short u16x8;
typedef __attribute__((ext_vector_type(4))) unsigned short u16x4;
typedef __attribute__((ext_vector_type(4))) float f32x4;

__device__ __forceinline__ u16 f2bf(float f) {
    uint32_t u = __float_as_uint(f);
    u += 0x7fffu + ((u >> 16) & 1u);   // RNE
    return (u16)(u >> 16);
}

__device__ __forceinline__ void gl2lds16(const void* g, void* l) {
    __builtin_amdgcn_global_load_lds(
        (const __attribute__((address_space(1))) void*)(uintptr_t)g,
        (__attribute__((address_space(3))) void*)(uint32_t)(uintptr_t)l,
        16, 0, 0);
}

#define BAR()    do { asm volatile("" ::: "memory"); __builtin_amdgcn_s_barrier(); asm volatile("" ::: "memory"); } while (0)
#define WAITV4() asm volatile("s_waitcnt vmcnt(4)" ::: "memory")
#define WAITV2() asm volatile("s_waitcnt vmcnt(2)" ::: "memory")
#define WAITV0() asm volatile("s_waitcnt vmcnt(0)" ::: "memory")
#define WAITL0() asm volatile("s_waitcnt lgkmcnt(0)" ::: "memory")
#define WAITL8() asm volatile("s_waitcnt lgkmcnt(8)" ::: "memory")
#define SCHED0() __builtin_amdgcn_sched_barrier(0)

// ---------------- fused prep: convert X | convert Wk | build Wmq/Wmv ----------------
// blocks [0,2048): X f32->bf16 (grid-stride, 8 passes)
// blocks [2048,2560): Wk slab f32->bf16 (one pass)
// blocks [2560,3584): Wmod[b] = W_slab + (A[idx_b]@B[idx_b])^T, bf16
// Read-once f32 sources use nontemporal loads (no cache pollution).

__device__ __forceinline__ u16x8 cvt8_nt(const float* __restrict__ src) {
    f32x4 a = __builtin_nontemporal_load(reinterpret_cast<const f32x4*>(src));
    f32x4 b = __builtin_nontemporal_load(reinterpret_cast<const f32x4*>(src) + 1);
    u16x8 o;
    o[0] = f2bf(a[0]); o[1] = f2bf(a[1]); o[2] = f2bf(a[2]); o[3] = f2bf(a[3]);
    o[4] = f2bf(b[0]); o[5] = f2bf(b[1]); o[6] = f2bf(b[2]); o[7] = f2bf(b[3]);
    return o;
}

__global__ __launch_bounds__(256) void k_prep(const float* __restrict__ x,
                                              const float* __restrict__ W,
                                              const float* __restrict__ Aq_pool,
                                              const float* __restrict__ Bq_pool,
                                              const float* __restrict__ Av_pool,
                                              const float* __restrict__ Bv_pool,
                                              const int* __restrict__ idx,
                                              u16* __restrict__ Xc,
                                              u16* __restrict__ Wk,
                                              u16* __restrict__ Wmq,
                                              u16* __restrict__ Wmv) {
    if (blockIdx.x < 2048) {                       // ---- X convert ----
        const int stride = 2048 * 256;
        for (int t = blockIdx.x * 256 + threadIdx.x; t * 8 < MROWS * DIM; t += stride) {
            const int i = t * 8;
            *reinterpret_cast<u16x8*>(Xc + i) = cvt8_nt(x + i);
        }
        return;
    }
    if (blockIdx.x < 2560) {                       // ---- Wk convert ----
        const int i = ((blockIdx.x - 2048) * 256 + threadIdx.x) * 8;
        *reinterpret_cast<u16x8*>(Wk + i) = cvt8_nt(W + (size_t)DIM * DIM + i);
        return;
    }
    // ---- build ----
    const int bb = blockIdx.x - 2560;
    const int b  = bb >> 7;
    const int s  = (bb >> 6) & 1;
    const int og = bb & 63;
    const int p  = idx[b];
    const float* A  = (s ? Av_pool : Aq_pool) + (size_t)p * DIM * RANK;
    const float* Bp = (s ? Bv_pool : Bq_pool) + (size_t)p * RANK * DIM;
    const float* Ws = W + (size_t)(s ? 2048 : 0) * DIM;
    u16* dst = (s ? Wmv : Wmq) + (size_t)b * DIM * DIM;

    const int t  = threadIdx.x;
    const int i0 = t * 4;
    float a[4][8];
    #pragma unroll
    for (int ii = 0; ii < 4; ++ii) {
        float4 a0 = reinterpret_cast<const float4*>(A + (size_t)(i0 + ii) * RANK)[0];
        float4 a1 = reinterpret_cast<const float4*>(A + (size_t)(i0 + ii) * RANK)[1];
        a[ii][0] = a0.x; a[ii][1] = a0.y; a[ii][2] = a0.z; a[ii][3] = a0.w;
        a[ii][4] = a1.x; a[ii][5] = a1.y; a[ii][6] = a1.z; a[ii][7] = a1.w;
    }
    for (int r = 0; r < 16; ++r) {
        const int o = og * 16 + r;
        float bv[8];
        #pragma unroll
        for (int rr = 0; rr < 8; ++rr) bv[rr] = Bp[(size_t)rr * DIM + o];
        f32x4 w = __builtin_nontemporal_load(
            reinterpret_cast<const f32x4*>(Ws + (size_t)o * DIM + i0));
        u16x4 ov;
        #pragma unroll
        for (int ii = 0; ii < 4; ++ii) {
            float d = 0.f;
            #pragma unroll
            for (int rr = 0; rr < 8; ++rr) d += a[ii][rr] * bv[rr];
            ov[ii] = f2bf(w[ii] + d);
        }
        *reinterpret_cast<u16x4*>(dst + (size_t)o * DIM + i0) = ov;
    }
}

// ---------------- 256x256 8-wave 8-phase GEMM (R9 pipeline, NT epilogue) ----------
// BK=64; LDS 2 buffers x (A 256x64 + B 256x64) = 128 KiB; 128B rows,
// swizzle: 16B group g of row r at slot g^(r&7) (measured 0-conflict),
// staged via pre-swizzled global source (rule #21).
// Fragment map (progressive halves): A m-frag f: rows wr*64+(f&3)*16+(f>>2)*128
// (f<4 -> A-half0); B n-frag n: rows wc*16+n*64 (n<2 -> B-half0).
// Stage order per tile: A0@ph0, B0@ph1, B1@ph2, A1@ph3 (of tile t+1).
// vmcnt ledger (2 loads/half; invariant {B1(t),A1(t)}=4 at tile start):
//   end ph0: vmcnt(4) retires B1(t); end ph1: vmcnt(4) retires A1(t);
//   end ph2: none; end ph3: vmcnt(4) retires A0,B0(t+1).
// Tail (tile 15): drain 4 -> 2 (ph0) -> 0 (ph1). All count-guaranteed.
// Epilogue stores are NONTEMPORAL: out (394MB, zero-reuse) must not evict
// X/W from L2/LLC (R9 FETCH=211MB vs ~98MB cold floor = write-pollution).

__device__ __forceinline__ void stage_half(const u16* __restrict__ mat, int row0, int tk,
                                           u16* dst, int wave, int lane) {
    const int lrow = lane >> 3;
    const int g    = (lane & 7) ^ lrow;          // pre-swizzled 16B group
    const u16* gp = mat + (size_t)(row0 + wave * 8 + lrow) * DIM + tk + g * 8;
    u16* lp = dst + wave * 8 * 64;               // wave-uniform LDS base
    gl2lds16(gp, lp);
    gl2lds16(gp + (size_t)64 * DIM, lp + 64 * 64);
}

__device__ __forceinline__ void ds_read_A(const u16* sA, int wr, int lane,
                                          int kx0, int kx1, int mh, short8 (&a)[4][2]) {
    #pragma unroll
    for (int f = 0; f < 4; ++f) {
        const int row = wr * 64 + f * 16 + mh * 128 + (lane & 15);
        a[f][0] = *reinterpret_cast<const short8*>(sA + row * 64 + kx0);
        a[f][1] = *reinterpret_cast<const short8*>(sA + row * 64 + kx1);
    }
}
__device__ __forceinline__ void ds_read_B(const u16* sB, int wc, int lane,
                                          int kx0, int kx1, int nh, short8 (&b)[2][2]) {
    #pragma unroll
    for (int f = 0; f < 2; ++f) {
        const int row = wc * 16 + (nh * 2 + f) * 64 + (lane & 15);
        b[f][0] = *reinterpret_cast<const short8*>(sB + row * 64 + kx0);
        b[f][1] = *reinterpret_cast<const short8*>(sB + row * 64 + kx1);
    }
}

template <int MH, int NH>
__device__ __forceinline__ void mfma_quad(const short8 (&a)[4][2], const short8 (&b)[2][2],
                                          f32x4 (&acc)[8][4]) {
    #pragma unroll
    for (int ks = 0; ks < 2; ++ks)
        #pragma unroll
        for (int f = 0; f < 4; ++f)
            #pragma unroll
            for (int g = 0; g < 2; ++g)
                acc[MH * 4 + f][NH * 2 + g] = __builtin_amdgcn_mfma_f32_16x16x32_bf16(
                    a[f][ks], b[g][ks], acc[MH * 4 + f][NH * 2 + g], 0, 0, 0);
}

#define MFMA_BLOCK(MH, NH, AREG, BREG)                  \
    do {                                                \
        BAR();                                          \
        WAITL0();                                       \
        SCHED0();                                       \
        __builtin_amdgcn_s_setprio(1);                  \
        mfma_quad<MH, NH>(AREG, BREG, acc);             \
        __builtin_amdgcn_s_setprio(0);                  \
        SCHED0();                                       \
    } while (0)

__global__ __launch_bounds__(512, 2) void k_gemm(const u16* __restrict__ Xc,
                                                 const u16* __restrict__ Wk,
                                                 const u16* __restrict__ Wmq,
                                                 const u16* __restrict__ Wmv,
                                                 const float* __restrict__ bias,
                                                 float* __restrict__ out) {
    extern __shared__ u16 lds[];               // 128 KiB
    const int tid  = threadIdx.x;
    const int lane = tid & 63, wave = tid >> 6;
    const int wr = wave >> 2, wc = wave & 3;   // 2M x 4N wave grid

    // bijective XCD swizzle (nwg=1536, 1536%8==0)
    const int orig = blockIdx.x;
    const int wg   = (orig & 7) * 192 + (orig >> 3);
    const int bn   = wg % 12;
    const int bm   = wg / 12;
    const int m0 = bm * 256, n0 = bn * 256;
    const int batch = m0 >> 12;

    const u16* Bmat;
    int nc;
    if (n0 < DIM)           { Bmat = Wmq + (size_t)batch * DIM * DIM; nc = n0; }
    else if (n0 < 2 * DIM)  { Bmat = Wk;                              nc = n0 - DIM; }
    else                    { Bmat = Wmv + (size_t)batch * DIM * DIM; nc = n0 - 2 * DIM; }

    const int kx0 = (((lane >> 4)    ) ^ (lane & 7)) * 8;
    const int kx1 = (((lane >> 4) + 4) ^ (lane & 7)) * 8;

    f32x4 acc[8][4] = {};

    // prologue: tile 0 fully into buffer 0, drain once
    stage_half(Xc,   m0,       0, lds,                    wave, lane);
    stage_half(Bmat, nc,       0, lds + 16384,            wave, lane);
    stage_half(Bmat, nc + 128, 0, lds + 16384 + 128 * 64, wave, lane);
    stage_half(Xc,   m0 + 128, 0, lds + 128 * 64,         wave, lane);
    WAITV0(); BAR();

    #pragma unroll 1
    for (int t = 0; t < 15; ++t) {
        const u16* sA = lds + (t & 1) * 32768;
        const u16* sB = sA + 16384;
        u16* wA = lds + ((t + 1) & 1) * 32768;
        u16* wB = wA + 16384;
        const int tk1 = (t + 1) * 64;
        short8 a_lo[4][2], a_hi[4][2], b0[2][2], b1[2][2];

        // ---- phase 0: read Ah0(8)+Bh0(4); stage A0(t+1); quad(0,0) ----
        ds_read_A(sA, wr, lane, kx0, kx1, 0, a_lo);
        ds_read_B(sB, wc, lane, kx0, kx1, 0, b0);
        stage_half(Xc, m0, tk1, wA, wave, lane);
        WAITL8();
        MFMA_BLOCK(0, 0, a_lo, b0);
        WAITV4(); BAR();               // retire B1(t) (read next phase)

        // ---- phase 1: read Bh1(4); stage B0(t+1); quad(0,1) ----
        ds_read_B(sB, wc, lane, kx0, kx1, 1, b1);
        stage_half(Bmat, nc, tk1, wB, wave, lane);
        MFMA_BLOCK(0, 1, a_lo, b1);
        WAITV4(); BAR();               // retire A1(t) (read next phase)

        // ---- phase 2: read Ah1(8); stage B1(t+1); quad(1,0) ----
        ds_read_A(sA, wr, lane, kx0, kx1, 1, a_hi);
        stage_half(Bmat, nc + 128, tk1, wB + 128 * 64, wave, lane);
        MFMA_BLOCK(1, 0, a_hi, b0);
        BAR();

        // ---- phase 3: no reads; stage A1(t+1); quad(1,1); boundary ----
        stage_half(Xc, m0 + 128, tk1, wA + 128 * 64, wave, lane);
        MFMA_BLOCK(1, 1, a_hi, b1);
        WAITV4(); BAR();               // retire A0(t+1), B0(t+1) (read at ph0)
    }

    // ---- peeled tail: tile 15, no staging; count-guaranteed drain ----
    {
        const u16* sA = lds + 32768;   // 15 & 1 == 1
        const u16* sB = sA + 16384;
        short8 a_lo[4][2], a_hi[4][2], b0[2][2], b1[2][2];

        ds_read_A(sA, wr, lane, kx0, kx1, 0, a_lo);
        ds_read_B(sB, wc, lane, kx0, kx1, 0, b0);
        WAITL8();
        MFMA_BLOCK(0, 0, a_lo, b0);
        WAITV2(); BAR();               // retire B1(15) before its read

        ds_read_B(sB, wc, lane, kx0, kx1, 1, b1);
        MFMA_BLOCK(0, 1, a_lo, b1);
        WAITV0(); BAR();               // retire A1(15) before its read

        ds_read_A(sA, wr, lane, kx0, kx1, 1, a_hi);
        MFMA_BLOCK(1, 0, a_hi, b0);
        BAR();

        MFMA_BLOCK(1, 1, a_hi, b1);
    }

    // ---------------- epilogue: bias + nontemporal store ----------------
    const int cn = wc * 16 + (lane & 15);      // col within 256-block, + ni*64
    float bcol[4];
    #pragma unroll
    for (int ni = 0; ni < 4; ++ni) bcol[ni] = bias[n0 + cn + ni * 64];
    #pragma unroll
    for (int mi = 0; mi < 8; ++mi) {
        const int rb = m0 + wr * 64 + (mi & 3) * 16 + (mi >> 2) * 128 + (lane >> 4) * 4;
        #pragma unroll
        for (int v = 0; v < 4; ++v) {
            const size_t row = (size_t)(rb + v);
            #pragma unroll
            for (int ni = 0; ni < 4; ++ni)
                __builtin_nontemporal_store(acc[mi][ni][v] + bcol[ni],
                                            &out[row * ODIM + (size_t)(n0 + cn + ni * 64)]);
        }
    }
}

extern "C" void kernel_launch(void* const* d_in, const int* in_sizes, int n_in,
                              void* d_out, int out_size, void* d_ws, size_t ws_size,
                              hipStream_t stream) {
    const float* x      = (const float*)d_in[0];
    const float* weight = (const float*)d_in[1];
    const float* bias   = (const float*)d_in[2];
    const float* Aq     = (const float*)d_in[3];
    const float* Bq     = (const float*)d_in[4];
    const float* Av     = (const float*)d_in[5];
    const float* Bv     = (const float*)d_in[6];
    const int*   idx    = (const int*)d_in[7];
    float* out = (float*)d_out;

    // workspace: Xc(64MB) | Wk(2MB) | Wmq(16MB) | Wmv(16MB) = 98MB
    u16* Xc  = (u16*)d_ws;
    u16* Wk  = Xc + (size_t)MROWS * DIM;
    u16* Wmq = Wk + (size_t)DIM * DIM;
    u16* Wmv = Wmq + (size_t)8 * DIM * DIM;

    hipFuncSetAttribute(reinterpret_cast<const void*>(k_gemm),
                        hipFuncAttributeMaxDynamicSharedMemorySize, 131072);

    k_prep<<<3584, 256, 0, stream>>>(x, weight, Aq, Bq, Av, Bv, idx, Xc, Wk, Wmq, Wmv);
    k_gemm<<<1536, 512, 131072, stream>>>(Xc, Wk, Wmq, Wmv, bias, out);
}

// Round 15
// 279.146 us; speedup vs baseline: 1.1420x; 1.0225x over previous
//
#include <hip/hip_runtime.h>
#include <hip/hip_bf16.h>
#include <stdint.h>

#define DIM   1024
#define ODIM  3072
#define MROWS 32768   // B(8) * N(4096)
#define RANK  8

typedef unsigned short u16;
typedef __attribute__((ext_vector_type(8))) short short8;
typedef __attribute__((ext_vector_type(8))) unsigned short u16x8;
typedef __attribute__((ext_vector_type(4))) unsigned short u16x4;
typedef __attribute__((ext_vector_type(4))) float f32x4;

__device__ __forceinline__ u16 f2bf(float f) {
    uint32_t u = __float_as_uint(f);
    u += 0x7fffu + ((u >> 16) & 1u);   // RNE
    return (u16)(u >> 16);
}

__device__ __forceinline__ void gl2lds16(const void* g, void* l) {
    __builtin_amdgcn_global_load_lds(
        (const __attribute__((address_space(1))) void*)(uintptr_t)g,
        (__attribute__((address_space(3))) void*)(uint32_t)(uintptr_t)l,
        16, 0, 0);
}

#define BAR()    do { asm volatile("" ::: "memory"); __builtin_amdgcn_s_barrier(); asm volatile("" ::: "memory"); } while (0)
#define WAITV4() asm volatile("s_waitcnt vmcnt(4)" ::: "memory")
#define WAITV2() asm volatile("s_waitcnt vmcnt(2)" ::: "memory")
#define WAITV0() asm volatile("s_waitcnt vmcnt(0)" ::: "memory")
#define WAITL0() asm volatile("s_waitcnt lgkmcnt(0)" ::: "memory")
#define WAITL8() asm volatile("s_waitcnt lgkmcnt(8)" ::: "memory")
#define SCHED0() __builtin_amdgcn_sched_barrier(0)

// ---------------- fused prep: convert X | convert Wk | build Wmq/Wmv ----------------
// blocks [0,2048): X f32->bf16 (grid-stride, 8 passes)
// blocks [2048,2560): Wk slab f32->bf16 (one pass)
// blocks [2560,3584): Wmod[b] = W_slab + (A[idx_b]@B[idx_b])^T, bf16
// Read-once f32 sources use nontemporal LOADS (no cache pollution).
// (NT STORES were tried in R14 and reverted: +32% WRITE amplification —
//  L2 write-combining of the 4B-lane stores is load-bearing.)

__device__ __forceinline__ u16x8 cvt8_nt(const float* __restrict__ src) {
    f32x4 a = __builtin_nontemporal_load(reinterpret_cast<const f32x4*>(src));
    f32x4 b = __builtin_nontemporal_load(reinterpret_cast<const f32x4*>(src) + 1);
    u16x8 o;
    o[0] = f2bf(a[0]); o[1] = f2bf(a[1]); o[2] = f2bf(a[2]); o[3] = f2bf(a[3]);
    o[4] = f2bf(b[0]); o[5] = f2bf(b[1]); o[6] = f2bf(b[2]); o[7] = f2bf(b[3]);
    return o;
}

__global__ __launch_bounds__(256) void k_prep(const float* __restrict__ x,
                                              const float* __restrict__ W,
                                              const float* __restrict__ Aq_pool,
                                              const float* __restrict__ Bq_pool,
                                              const float* __restrict__ Av_pool,
                                              const float* __restrict__ Bv_pool,
                                              const int* __restrict__ idx,
                                              u16* __restrict__ Xc,
                                              u16* __restrict__ Wk,
                                              u16* __restrict__ Wmq,
                                              u16* __restrict__ Wmv) {
    if (blockIdx.x < 2048) {                       // ---- X convert ----
        const int stride = 2048 * 256;
        for (int t = blockIdx.x * 256 + threadIdx.x; t * 8 < MROWS * DIM; t += stride) {
            const int i = t * 8;
            *reinterpret_cast<u16x8*>(Xc + i) = cvt8_nt(x + i);
        }
        return;
    }
    if (blockIdx.x < 2560) {                       // ---- Wk convert ----
        const int i = ((blockIdx.x - 2048) * 256 + threadIdx.x) * 8;
        *reinterpret_cast<u16x8*>(Wk + i) = cvt8_nt(W + (size_t)DIM * DIM + i);
        return;
    }
    // ---- build ----
    const int bb = blockIdx.x - 2560;
    const int b  = bb >> 7;
    const int s  = (bb >> 6) & 1;
    const int og = bb & 63;
    const int p  = idx[b];
    const float* A  = (s ? Av_pool : Aq_pool) + (size_t)p * DIM * RANK;
    const float* Bp = (s ? Bv_pool : Bq_pool) + (size_t)p * RANK * DIM;
    const float* Ws = W + (size_t)(s ? 2048 : 0) * DIM;
    u16* dst = (s ? Wmv : Wmq) + (size_t)b * DIM * DIM;

    const int t  = threadIdx.x;
    const int i0 = t * 4;
    float a[4][8];
    #pragma unroll
    for (int ii = 0; ii < 4; ++ii) {
        float4 a0 = reinterpret_cast<const float4*>(A + (size_t)(i0 + ii) * RANK)[0];
        float4 a1 = reinterpret_cast<const float4*>(A + (size_t)(i0 + ii) * RANK)[1];
        a[ii][0] = a0.x; a[ii][1] = a0.y; a[ii][2] = a0.z; a[ii][3] = a0.w;
        a[ii][4] = a1.x; a[ii][5] = a1.y; a[ii][6] = a1.z; a[ii][7] = a1.w;
    }
    for (int r = 0; r < 16; ++r) {
        const int o = og * 16 + r;
        float bv[8];
        #pragma unroll
        for (int rr = 0; rr < 8; ++rr) bv[rr] = Bp[(size_t)rr * DIM + o];
        f32x4 w = __builtin_nontemporal_load(
            reinterpret_cast<const f32x4*>(Ws + (size_t)o * DIM + i0));
        u16x4 ov;
        #pragma unroll
        for (int ii = 0; ii < 4; ++ii) {
            float d = 0.f;
            #pragma unroll
            for (int rr = 0; rr < 8; ++rr) d += a[ii][rr] * bv[rr];
            ov[ii] = f2bf(w[ii] + d);
        }
        *reinterpret_cast<u16x4*>(dst + (size_t)o * DIM + i0) = ov;
    }
}

// ---------------- 256x256 8-wave 8-phase GEMM (R9 pipeline) ----------------
// BK=64; LDS 2 buffers x (A 256x64 + B 256x64) = 128 KiB; 128B rows,
// swizzle: 16B group g of row r at slot g^(r&7) (measured 0-conflict),
// staged via pre-swizzled global source (rule #21).
// Fragment map (progressive halves): A m-frag f: rows wr*64+(f&3)*16+(f>>2)*128
// (f<4 -> A-half0); B n-frag n: rows wc*16+n*64 (n<2 -> B-half0).
// Stage order per tile: A0@ph0, B0@ph1, B1@ph2, A1@ph3 (of tile t+1).
// vmcnt ledger (2 loads/half; invariant {B1(t),A1(t)}=4 at tile start):
//   end ph0: vmcnt(4) retires B1(t); end ph1: vmcnt(4) retires A1(t);
//   end ph2: none; end ph3: vmcnt(4) retires A0,B0(t+1).
// Tail (tile 15): drain 4 -> 2 (ph0) -> 0 (ph1). All count-guaranteed.

__device__ __forceinline__ void stage_half(const u16* __restrict__ mat, int row0, int tk,
                                           u16* dst, int wave, int lane) {
    const int lrow = lane >> 3;
    const int g    = (lane & 7) ^ lrow;          // pre-swizzled 16B group
    const u16* gp = mat + (size_t)(row0 + wave * 8 + lrow) * DIM + tk + g * 8;
    u16* lp = dst + wave * 8 * 64;               // wave-uniform LDS base
    gl2lds16(gp, lp);
    gl2lds16(gp + (size_t)64 * DIM, lp + 64 * 64);
}

__device__ __forceinline__ void ds_read_A(const u16* sA, int wr, int lane,
                                          int kx0, int kx1, int mh, short8 (&a)[4][2]) {
    #pragma unroll
    for (int f = 0; f < 4; ++f) {
        const int row = wr * 64 + f * 16 + mh * 128 + (lane & 15);
        a[f][0] = *reinterpret_cast<const short8*>(sA + row * 64 + kx0);
        a[f][1] = *reinterpret_cast<const short8*>(sA + row * 64 + kx1);
    }
}
__device__ __forceinline__ void ds_read_B(const u16* sB, int wc, int lane,
                                          int kx0, int kx1, int nh, short8 (&b)[2][2]) {
    #pragma unroll
    for (int f = 0; f < 2; ++f) {
        const int row = wc * 16 + (nh * 2 + f) * 64 + (lane & 15);
        b[f][0] = *reinterpret_cast<const short8*>(sB + row * 64 + kx0);
        b[f][1] = *reinterpret_cast<const short8*>(sB + row * 64 + kx1);
    }
}

template <int MH, int NH>
__device__ __forceinline__ void mfma_quad(const short8 (&a)[4][2], const short8 (&b)[2][2],
                                          f32x4 (&acc)[8][4]) {
    #pragma unroll
    for (int ks = 0; ks < 2; ++ks)
        #pragma unroll
        for (int f = 0; f < 4; ++f)
            #pragma unroll
            for (int g = 0; g < 2; ++g)
                acc[MH * 4 + f][NH * 2 + g] = __builtin_amdgcn_mfma_f32_16x16x32_bf16(
                    a[f][ks], b[g][ks], acc[MH * 4 + f][NH * 2 + g], 0, 0, 0);
}

#define MFMA_BLOCK(MH, NH, AREG, BREG)                  \
    do {                                                \
        BAR();                                          \
        WAITL0();                                       \
        SCHED0();                                       \
        __builtin_amdgcn_s_setprio(1);                  \
        mfma_quad<MH, NH>(AREG, BREG, acc);             \
        __builtin_amdgcn_s_setprio(0);                  \
        SCHED0();                                       \
    } while (0)

__global__ __launch_bounds__(512, 2) void k_gemm(const u16* __restrict__ Xc,
                                                 const u16* __restrict__ Wk,
                                                 const u16* __restrict__ Wmq,
                                                 const u16* __restrict__ Wmv,
                                                 const float* __restrict__ bias,
                                                 float* __restrict__ out) {
    extern __shared__ u16 lds[];               // 128 KiB
    const int tid  = threadIdx.x;
    const int lane = tid & 63, wave = tid >> 6;
    const int wr = wave >> 2, wc = wave & 3;   // 2M x 4N wave grid

    // bijective XCD swizzle (nwg=1536, 1536%8==0)
    const int orig = blockIdx.x;
    const int wg   = (orig & 7) * 192 + (orig >> 3);
    const int bn   = wg % 12;
    const int bm   = wg / 12;
    const int m0 = bm * 256, n0 = bn * 256;
    const int batch = m0 >> 12;

    const u16* Bmat;
    int nc;
    if (n0 < DIM)           { Bmat = Wmq + (size_t)batch * DIM * DIM; nc = n0; }
    else if (n0 < 2 * DIM)  { Bmat = Wk;                              nc = n0 - DIM; }
    else                    { Bmat = Wmv + (size_t)batch * DIM * DIM; nc = n0 - 2 * DIM; }

    const int kx0 = (((lane >> 4)    ) ^ (lane & 7)) * 8;
    const int kx1 = (((lane >> 4) + 4) ^ (lane & 7)) * 8;

    f32x4 acc[8][4] = {};

    // prologue: tile 0 fully into buffer 0, drain once
    stage_half(Xc,   m0,       0, lds,                    wave, lane);
    stage_half(Bmat, nc,       0, lds + 16384,            wave, lane);
    stage_half(Bmat, nc + 128, 0, lds + 16384 + 128 * 64, wave, lane);
    stage_half(Xc,   m0 + 128, 0, lds + 128 * 64,         wave, lane);
    WAITV0(); BAR();

    #pragma unroll 1
    for (int t = 0; t < 15; ++t) {
        const u16* sA = lds + (t & 1) * 32768;
        const u16* sB = sA + 16384;
        u16* wA = lds + ((t + 1) & 1) * 32768;
        u16* wB = wA + 16384;
        const int tk1 = (t + 1) * 64;
        short8 a_lo[4][2], a_hi[4][2], b0[2][2], b1[2][2];

        // ---- phase 0: read Ah0(8)+Bh0(4); stage A0(t+1); quad(0,0) ----
        ds_read_A(sA, wr, lane, kx0, kx1, 0, a_lo);
        ds_read_B(sB, wc, lane, kx0, kx1, 0, b0);
        stage_half(Xc, m0, tk1, wA, wave, lane);
        WAITL8();
        MFMA_BLOCK(0, 0, a_lo, b0);
        WAITV4(); BAR();               // retire B1(t) (read next phase)

        // ---- phase 1: read Bh1(4); stage B0(t+1); quad(0,1) ----
        ds_read_B(sB, wc, lane, kx0, kx1, 1, b1);
        stage_half(Bmat, nc, tk1, wB, wave, lane);
        MFMA_BLOCK(0, 1, a_lo, b1);
        WAITV4(); BAR();               // retire A1(t) (read next phase)

        // ---- phase 2: read Ah1(8); stage B1(t+1); quad(1,0) ----
        ds_read_A(sA, wr, lane, kx0, kx1, 1, a_hi);
        stage_half(Bmat, nc + 128, tk1, wB + 128 * 64, wave, lane);
        MFMA_BLOCK(1, 0, a_hi, b0);
        BAR();

        // ---- phase 3: no reads; stage A1(t+1); quad(1,1); boundary ----
        stage_half(Xc, m0 + 128, tk1, wA + 128 * 64, wave, lane);
        MFMA_BLOCK(1, 1, a_hi, b1);
        WAITV4(); BAR();               // retire A0(t+1), B0(t+1) (read at ph0)
    }

    // ---- peeled tail: tile 15, no staging; count-guaranteed drain ----
    {
        const u16* sA = lds + 32768;   // 15 & 1 == 1
        const u16* sB = sA + 16384;
        short8 a_lo[4][2], a_hi[4][2], b0[2][2], b1[2][2];

        ds_read_A(sA, wr, lane, kx0, kx1, 0, a_lo);
        ds_read_B(sB, wc, lane, kx0, kx1, 0, b0);
        WAITL8();
        MFMA_BLOCK(0, 0, a_lo, b0);
        WAITV2(); BAR();               // retire B1(15) before its read

        ds_read_B(sB, wc, lane, kx0, kx1, 1, b1);
        MFMA_BLOCK(0, 1, a_lo, b1);
        WAITV0(); BAR();               // retire A1(15) before its read

        ds_read_A(sA, wr, lane, kx0, kx1, 1, a_hi);
        MFMA_BLOCK(1, 0, a_hi, b0);
        BAR();

        MFMA_BLOCK(1, 1, a_hi, b1);
    }

    // ---------------- epilogue: bias + store (plain; L2 write-combining) ----------
    const int cn = wc * 16 + (lane & 15);      // col within 256-block, + ni*64
    float bcol[4];
    #pragma unroll
    for (int ni = 0; ni < 4; ++ni) bcol[ni] = bias[n0 + cn + ni * 64];
    #pragma unroll
    for (int mi = 0; mi < 8; ++mi) {
        const int rb = m0 + wr * 64 + (mi & 3) * 16 + (mi >> 2) * 128 + (lane >> 4) * 4;
        #pragma unroll
        for (int v = 0; v < 4; ++v) {
            const size_t row = (size_t)(rb + v);
            #pragma unroll
            for (int ni = 0; ni < 4; ++ni)
                out[row * ODIM + (size_t)(n0 + cn + ni * 64)] = acc[mi][ni][v] + bcol[ni];
        }
    }
}

extern "C" void kernel_launch(void* const* d_in, const int* in_sizes, int n_in,
                              void* d_out, int out_size, void* d_ws, size_t ws_size,
                              hipStream_t stream) {
    const float* x      = (const float*)d_in[0];
    const float* weight = (const float*)d_in[1];
    const float* bias   = (const float*)d_in[2];
    const float* Aq     = (const float*)d_in[3];
    const float* Bq     = (const float*)d_in[4];
    const float* Av     = (const float*)d_in[5];
    const float* Bv     = (const float*)d_in[6];
    const int*   idx    = (const int*)d_in[7];
    float* out = (float*)d_out;

    // workspace: Xc(64MB) | Wk(2MB) | Wmq(16MB) | Wmv(16MB) = 98MB
    u16* Xc  = (u16*)d_ws;
    u16* Wk  = Xc + (size_t)MROWS * DIM;
    u16* Wmq = Wk + (size_t)DIM * DIM;
    u16* Wmv = Wmq + (size_t)8 * DIM * DIM;

    hipFuncSetAttribute(reinterpret_cast<const void*>(k_gemm),
                        hipFuncAttributeMaxDynamicSharedMemorySize, 131072);

    k_prep<<<3584, 256, 0, stream>>>(x, weight, Aq, Bq, Av, Bv, idx, Xc, Wk, Wmq, Wmv);
    k_gemm<<<1536, 512, 131072, stream>>>(Xc, Wk, Wmq, Wmv, bias, out);
}